// Round 1
// baseline (1169.947 us; speedup 1.0000x reference)
//
#include <hip/hip_runtime.h>
#include <hip/hip_bf16.h>
#include <math.h>
#include <stdint.h>

#define N_NODES 100000
#define N_EDGES 1000000
#define F_IN    128
#define ED_DIM  16
#define H_HEADS 5
#define C_CH    16
#define HC      80
#define NEG_SLOPE 0.2f

#define SCAN_B 256
#define SCAN_G ((N_NODES + SCAN_B - 1) / SCAN_B)   // 391
#define DBIN 64
#define EPAD 8   // padding entries on src_s/perm; 8 pad rows on eattr_s

// ================= CSR build (graph is static across layers) =================

__global__ void k_hist(const int* __restrict__ dst, int* __restrict__ count) {
    const int e = blockIdx.x * 256 + threadIdx.x;
    if (e < N_EDGES) atomicAdd(count + dst[e], 1);
}

__global__ __launch_bounds__(SCAN_B) void k_part(const int* __restrict__ count,
                                                 int* __restrict__ partial) {
    const int i = blockIdx.x * SCAN_B + threadIdx.x;
    int v = (i < N_NODES) ? count[i] : 0;
    const int lane = threadIdx.x & 63;
    const int w    = threadIdx.x >> 6;
    __shared__ int ws[SCAN_B / 64];
    #pragma unroll
    for (int o = 32; o > 0; o >>= 1) v += __shfl_down(v, o, 64);
    if (lane == 0) ws[w] = v;
    __syncthreads();
    if (threadIdx.x == 0) {
        int s = 0;
        #pragma unroll
        for (int k = 0; k < SCAN_B / 64; ++k) s += ws[k];
        partial[blockIdx.x] = s;
    }
}

__global__ __launch_bounds__(512) void k_scanp(const int* __restrict__ partial,
                                               int* __restrict__ blockoff,
                                               int* __restrict__ rowstart) {
    __shared__ int s[512];
    const int t = threadIdx.x;
    int v = (t < SCAN_G) ? partial[t] : 0;
    s[t] = v;
    __syncthreads();
    for (int o = 1; o < 512; o <<= 1) {
        int u = (t >= o) ? s[t - o] : 0;
        __syncthreads();
        s[t] += u;
        __syncthreads();
    }
    if (t < SCAN_G) blockoff[t] = (t == 0) ? 0 : s[t - 1];
    if (t == 0) rowstart[N_NODES] = s[511];
}

__global__ __launch_bounds__(SCAN_B) void k_apply(const int* __restrict__ count,
                                                  const int* __restrict__ blockoff,
                                                  int* __restrict__ rowstart) {
    __shared__ int s[SCAN_B];
    const int i = blockIdx.x * SCAN_B + threadIdx.x;
    const int t = threadIdx.x;
    const int v = (i < N_NODES) ? count[i] : 0;
    s[t] = v;
    __syncthreads();
    for (int o = 1; o < SCAN_B; o <<= 1) {
        int u = (t >= o) ? s[t - o] : 0;
        __syncthreads();
        s[t] += u;
        __syncthreads();
    }
    if (i < N_NODES) rowstart[i] = blockoff[blockIdx.x] + (s[t] - v);
}

// place edge into CSR slot; src_s stores src*HC (pre-scaled for the hot loop);
// if COPY, also copy the 64B eattr row into CSR order (replaces k_permea pass)
template<bool COPY>
__global__ void k_place(const int* __restrict__ src, const int* __restrict__ dst,
                        const int* __restrict__ rowstart, int* __restrict__ cursor,
                        int* __restrict__ perm, int* __restrict__ src_s,
                        const float* __restrict__ eattr, float* __restrict__ eattr_s) {
    const int e = blockIdx.x * 256 + threadIdx.x;
    if (e >= N_EDGES) return;
    const int d = dst[e];
    const int pos = rowstart[d] + atomicAdd(cursor + d, 1);
    src_s[pos] = src[e] * HC;
    if (COPY) {
        const float4* s4 = (const float4*)(eattr + (size_t)e * ED_DIM);
        float4* d4 = (float4*)(eattr_s + (size_t)pos * ED_DIM);
        d4[0] = s4[0]; d4[1] = s4[1]; d4[2] = s4[2]; d4[3] = s4[3];
    } else {
        perm[pos] = e;
    }
}

// ====== degree-bucket counting sort of nodes (descending degree) =============
__global__ __launch_bounds__(256) void k_deghist(const int* __restrict__ cnt,
                                                 int* __restrict__ dhist) {
    __shared__ int lh[DBIN];
    const int t = threadIdx.x;
    if (t < DBIN) lh[t] = 0;
    __syncthreads();
    const int n = blockIdx.x * 256 + t;
    if (n < N_NODES) atomicAdd(&lh[min(cnt[n], DBIN - 1)], 1);
    __syncthreads();
    if (t < DBIN && lh[t] > 0) atomicAdd(dhist + t, lh[t]);
}

// also zeroes the perm/src_s padding (ws is re-poisoned before every launch)
__global__ void k_degoff(const int* __restrict__ dhist, int* __restrict__ dcur,
                         int* __restrict__ perm, int* __restrict__ src_s) {
    if (threadIdx.x == 0) {
        int off = 0;
        for (int b = DBIN - 1; b >= 0; --b) { dcur[b] = off; off += dhist[b]; }
        for (int i = 0; i < EPAD; ++i) {
            perm[N_EDGES + i]  = 0;
            src_s[N_EDGES + i] = 0;
        }
    }
}

__global__ __launch_bounds__(256) void k_degplace(const int* __restrict__ cnt,
                                                  int* __restrict__ dcur,
                                                  int* __restrict__ nodeord) {
    __shared__ int lh[DBIN];
    __shared__ int base[DBIN];
    const int t = threadIdx.x;
    if (t < DBIN) lh[t] = 0;
    __syncthreads();
    const int n = blockIdx.x * 256 + t;
    int b = 0, r = 0;
    if (n < N_NODES) {
        b = min(cnt[n], DBIN - 1);
        r = atomicAdd(&lh[b], 1);
    }
    __syncthreads();
    if (t < DBIN && lh[t] > 0) base[t] = atomicAdd(dcur + t, lh[t]);
    __syncthreads();
    if (n < N_NODES) nodeord[base[b] + r] = n;
}

// ====== fused dual node transform: xl = A@WL^T+bL, xr = A@WR^T+bR ============
template<int DIN>
__global__ __launch_bounds__(320) void k_xform2(
    const float* __restrict__ A,
    const float* __restrict__ WL, const float* __restrict__ bL,
    const float* __restrict__ WR, const float* __restrict__ bR,
    float* __restrict__ outL, float* __restrict__ outR, int nn) {
    __shared__ float As[16][68];
    __shared__ float WsL[16][80];
    __shared__ float WsR[16][80];
    const int t  = threadIdx.x;
    const int n0 = blockIdx.x * 64;
    const int tn = (t & 15) * 4;
    const int tj = (t >> 4) * 4;
    float4 accL[4], accR[4];
    #pragma unroll
    for (int u = 0; u < 4; ++u) {
        accL[u] = make_float4(0.f, 0.f, 0.f, 0.f);
        accR[u] = make_float4(0.f, 0.f, 0.f, 0.f);
    }

    for (int k0 = 0; k0 < DIN; k0 += 16) {
        __syncthreads();
        for (int i = t; i < 64*16; i += 320) {
            int nl = i >> 4, kk = i & 15;
            int n = n0 + nl;
            As[kk][nl] = (n < nn) ? A[(size_t)n*DIN + k0 + kk] : 0.f;
        }
        for (int i = t; i < 80*16; i += 320) {
            int jj = i >> 4, kk = i & 15;
            WsL[kk][jj] = WL[(size_t)jj*DIN + k0 + kk];
            WsR[kk][jj] = WR[(size_t)jj*DIN + k0 + kk];
        }
        __syncthreads();
        #pragma unroll
        for (int k = 0; k < 16; ++k) {
            const float4 av = *(const float4*)&As[k][tn];
            const float4 wl = *(const float4*)&WsL[k][tj];
            const float4 wr = *(const float4*)&WsR[k][tj];
            accL[0].x += av.x*wl.x; accL[0].y += av.x*wl.y; accL[0].z += av.x*wl.z; accL[0].w += av.x*wl.w;
            accL[1].x += av.y*wl.x; accL[1].y += av.y*wl.y; accL[1].z += av.y*wl.z; accL[1].w += av.y*wl.w;
            accL[2].x += av.z*wl.x; accL[2].y += av.z*wl.y; accL[2].z += av.z*wl.z; accL[2].w += av.z*wl.w;
            accL[3].x += av.w*wl.x; accL[3].y += av.w*wl.y; accL[3].z += av.w*wl.z; accL[3].w += av.w*wl.w;
            accR[0].x += av.x*wr.x; accR[0].y += av.x*wr.y; accR[0].z += av.x*wr.z; accR[0].w += av.x*wr.w;
            accR[1].x += av.y*wr.x; accR[1].y += av.y*wr.y; accR[1].z += av.y*wr.z; accR[1].w += av.y*wr.w;
            accR[2].x += av.z*wr.x; accR[2].y += av.z*wr.y; accR[2].z += av.z*wr.z; accR[2].w += av.z*wr.w;
            accR[3].x += av.w*wr.x; accR[3].y += av.w*wr.y; accR[3].z += av.w*wr.z; accR[3].w += av.w*wr.w;
        }
    }
    const float4 bvL = *(const float4*)(bL + tj);
    const float4 bvR = *(const float4*)(bR + tj);
    #pragma unroll
    for (int u = 0; u < 4; ++u) {
        int n = n0 + tn + u;
        if (n < nn) {
            float4 o;
            o.x = accL[u].x + bvL.x; o.y = accL[u].y + bvL.y;
            o.z = accL[u].z + bvL.z; o.w = accL[u].w + bvL.w;
            *(float4*)(outL + (size_t)n*HC + tj) = o;
            o.x = accR[u].x + bvR.x; o.y = accR[u].y + bvR.y;
            o.z = accR[u].z + bvR.z; o.w = accR[u].w + bvR.w;
            *(float4*)(outR + (size_t)n*HC + tj) = o;
        }
    }
}

// DPP rotate within each 16-lane row: pure VALU cross-lane, no LDS pipe.
// ctrl: 0x121 = row_ror:1, 0x122 = row_ror:2, 0x124 = row_ror:4, 0x128 = row_ror:8
template<int CTRL>
__device__ __forceinline__ float dpp_ror(float v) {
    return __int_as_float(__builtin_amdgcn_update_dpp(
        0, __float_as_int(v), CTRL, 0xF, 0xF, true));
}

// per-edge logit+exp+accumulate; ea row held in registers (a0..a3), em is 16
// register FMAs; 16-lane head reduction via DPP rotate-adds (no ds_swizzle).
__device__ __forceinline__ void edge_step_row(
    const float4& a0, const float4& a1, const float4& a2, const float4& a3,
    float xlv, float xrc, float attc,
    const float4& w0, const float4& w1, const float4& w2, const float4& w3,
    float gate, float& acc, float& l) {
    float m0 = w0.x*a0.x + w0.y*a0.y + w0.z*a0.z + w0.w*a0.w;
    float m1 = w1.x*a1.x + w1.y*a1.y + w1.z*a1.z + w1.w*a1.w;
    float m2 = w2.x*a2.x + w2.y*a2.y + w2.z*a2.z + w2.w*a2.w;
    float m3 = w3.x*a3.x + w3.y*a3.y + w3.z*a3.z + w3.w*a3.w;
    float v = xlv + xrc + ((m0 + m1) + (m2 + m3));
    v = fmaxf(v, 0.f) + NEG_SLOPE * fminf(v, 0.f);
    v *= attc;
    // rotate-reduce over the 16 channels of this head (all lanes get the sum)
    v += dpp_ror<0x121>(v);
    v += dpp_ror<0x122>(v);
    v += dpp_ror<0x124>(v);
    v += dpp_ror<0x128>(v);
    const float pt = __expf(v) * gate;
    acc += pt * xlv;
    l   += pt;
}

// ====== fused attention v6: 1 node per 80-thread group, 2 edges/iter ========
// thread = channel c (head = c>>4). Each thread loads the full 16-float eattr
// row (same address across group -> L1 broadcast); em entirely in registers;
// head reduction via DPP. xl gather keeps the 4-deep prefetch pipeline.
// src_s is pre-scaled by HC. Pads make all prefetches in-bounds; pad-driven
// garbage is bounded (exp finite) and killed by gate=0.
template<bool SORTED>
__global__ __launch_bounds__(320) void k_fused6(
    const float* __restrict__ xl, const float* __restrict__ xr,
    const float* __restrict__ ea,   // eattr_s if SORTED, raw eattr otherwise
    const float* __restrict__ we, const float* __restrict__ att,
    const int* __restrict__ perm, const int* __restrict__ src_s,
    const int* __restrict__ rowstart, const int* __restrict__ nodeord,
    const float* __restrict__ bias, float* __restrict__ out, int relu) {
    const int t = threadIdx.x;
    const int group = t / 80;
    const int c = t - group * 80;
    const int idx = blockIdx.x * 4 + group;
    if (idx >= N_NODES) return;
    const int n = nodeord[idx];

    const float4* w4 = (const float4*)(we + c * ED_DIM);
    const float4 w0 = w4[0], w1 = w4[1], w2 = w4[2], w3 = w4[3];
    const float attc = att[c];
    const float bc   = bias[c];
    const float xrc  = xr[n * HC + c];

    const int rs = rowstart[n], re = rowstart[n + 1];
    float l = 0.f, acc = 0.f;

    if (rs < re) {
        // preamble: xl values for p, p+1 in flight; src offsets for p+2, p+3
        const int o0 = src_s[rs];
        const int o1 = src_s[rs + 1];
        int sA = src_s[rs + 2];
        int sB = src_s[rs + 3];
        float xlA = xl[o0 + c];
        float xlB = xl[o1 + c];

        for (int p = rs; p < re; p += 2) {
            const float xl0 = xlA, xl1 = xlB;
            // issue ea row loads for edges p, p+1 (uniform per group)
            const int e0 = SORTED ? p       : perm[p];
            const int e1 = SORTED ? (p + 1) : perm[p + 1];
            const float4* ra = (const float4*)(ea + (size_t)e0 * ED_DIM);
            const float4* rb = (const float4*)(ea + (size_t)e1 * ED_DIM);
            const float4 a0 = ra[0], a1 = ra[1], a2 = ra[2], a3 = ra[3];
            const float4 b0 = rb[0], b1 = rb[1], b2 = rb[2], b3 = rb[3];
            // issue xl gathers for p+2, p+3; src offsets for p+4, p+5
            xlA = xl[sA + c];
            xlB = xl[sB + c];
            sA = src_s[p + 4];
            sB = src_s[p + 5];

            edge_step_row(a0, a1, a2, a3, xl0, xrc, attc, w0, w1, w2, w3,
                          1.f, acc, l);
            const float g1 = (p + 1 < re) ? 1.f : 0.f;
            edge_step_row(b0, b1, b2, b3, xl1, xrc, attc, w0, w1, w2, w3,
                          g1, acc, l);
        }
    }
    float o = acc / (l + 1e-16f) + bc;
    if (relu) o = fmaxf(o, 0.f);
    out[n * HC + c] = o;
}

extern "C" void kernel_launch(void* const* d_in, const int* in_sizes, int n_in,
                              void* d_out, int out_size, void* d_ws, size_t ws_size,
                              hipStream_t stream) {
    (void)in_sizes; (void)n_in; (void)out_size;
    const float* x     = (const float*)d_in[0];
    const int*   ei    = (const int*)d_in[1];
    const float* eattr = (const float*)d_in[2];
    const int* srcp = ei;
    const int* dstp = ei + N_EDGES;

    // workspace layout
    float* h      = (float*)d_ws;                            // N*80
    float* xl     = h  + (size_t)N_NODES*HC;                 // N*80
    float* xr     = xl + (size_t)N_NODES*HC;                 // N*80
    int* rowstart = (int*)(xr + (size_t)N_NODES*HC);         // N+1
    int* cursor   = rowstart + (N_NODES + 1);                // N
    int* perm     = cursor + N_NODES;                        // E + EPAD
    int* src_s    = perm + N_EDGES + EPAD;                   // E + EPAD
    int* partial  = src_s + N_EDGES + EPAD;                  // SCAN_G
    int* blockoff = partial + SCAN_G;                        // SCAN_G
    int* dhist    = blockoff + SCAN_G;                       // DBIN
    int* dcur     = dhist + DBIN;                            // DBIN
    int* nodeord  = dcur + DBIN;                             // N
    // 64B-align eattr_s: every row is read with dwordx4 in the hot loop
    float* eattr_s = (float*)(((uintptr_t)(nodeord + N_NODES) + 63) &
                              ~(uintptr_t)63);               // (E+8)*16 (optional)
    float* outp   = (float*)d_out;

    const size_t need_sorted =
        (size_t)((char*)(eattr_s + (size_t)(N_EDGES + EPAD) * ED_DIM) - (char*)d_ws);
    const bool use_sorted = (ws_size >= need_sorted);

    const dim3 bx(320);
    const dim3 gx((N_NODES + 63) / 64);
    const dim3 gf((N_NODES + 3) / 4);
    const dim3 geb((N_EDGES + 255) / 256);
    const dim3 gnb((N_NODES + 255) / 256);

    // ---- build CSR by destination + degree-sorted node order (once) ----
    hipMemsetAsync(cursor, 0, (size_t)N_NODES * sizeof(int), stream);
    hipMemsetAsync(dhist, 0, DBIN * sizeof(int), stream);
    k_hist<<<geb, 256, 0, stream>>>(dstp, cursor);
    k_part<<<SCAN_G, SCAN_B, 0, stream>>>(cursor, partial);
    k_scanp<<<1, 512, 0, stream>>>(partial, blockoff, rowstart);
    k_apply<<<SCAN_G, SCAN_B, 0, stream>>>(cursor, blockoff, rowstart);
    k_deghist<<<gnb, 256, 0, stream>>>(cursor, dhist);
    k_degoff<<<1, 64, 0, stream>>>(dhist, dcur, perm, src_s);
    k_degplace<<<gnb, 256, 0, stream>>>(cursor, dcur, nodeord);
    hipMemsetAsync(cursor, 0, (size_t)N_NODES * sizeof(int), stream);
    if (use_sorted) {
        k_place<true><<<geb, 256, 0, stream>>>(srcp, dstp, rowstart, cursor,
                                               perm, src_s, eattr, eattr_s);
    } else {
        k_place<false><<<geb, 256, 0, stream>>>(srcp, dstp, rowstart, cursor,
                                                perm, src_s, eattr, eattr_s);
    }

    for (int L = 0; L < 3; ++L) {
        const float* in   = (L == 0) ? x : h;
        float*       oacc = (L == 2) ? outp : h;
        const float* wl   = (const float*)d_in[3 + L*7 + 0];
        const float* bl   = (const float*)d_in[3 + L*7 + 1];
        const float* wr   = (const float*)d_in[3 + L*7 + 2];
        const float* br   = (const float*)d_in[3 + L*7 + 3];
        const float* we   = (const float*)d_in[3 + L*7 + 4];
        const float* att  = (const float*)d_in[3 + L*7 + 5];
        const float* bias = (const float*)d_in[3 + L*7 + 6];

        if (L == 0) {
            k_xform2<F_IN><<<gx, bx, 0, stream>>>(in, wl, bl, wr, br, xl, xr, N_NODES);
        } else {
            k_xform2<HC><<<gx, bx, 0, stream>>>(in, wl, bl, wr, br, xl, xr, N_NODES);
        }
        if (use_sorted) {
            k_fused6<true><<<gf, bx, 0, stream>>>(xl, xr, eattr_s, we, att, perm,
                                                  src_s, rowstart, nodeord, bias,
                                                  oacc, (L < 2) ? 1 : 0);
        } else {
            k_fused6<false><<<gf, bx, 0, stream>>>(xl, xr, eattr, we, att, perm,
                                                   src_s, rowstart, nodeord, bias,
                                                   oacc, (L < 2) ? 1 : 0);
        }
    }
}

// Round 2
// 1009.339 us; speedup vs baseline: 1.1591x; 1.1591x over previous
//
#include <hip/hip_runtime.h>
#include <hip/hip_bf16.h>
#include <math.h>
#include <stdint.h>

#define N_NODES 100000
#define N_EDGES 1000000
#define F_IN    128
#define ED_DIM  16
#define H_HEADS 5
#define C_CH    16
#define HC      80
#define NEG_SLOPE 0.2f

#define SCAN_B 256
#define SCAN_G ((N_NODES + SCAN_B - 1) / SCAN_B)   // 391
#define DBIN 64
#define EPAD 8   // padding entries on src_s/perm; 8 pad rows on eattr_s

// ================= CSR build (graph is static across layers) =================

__global__ void k_hist(const int* __restrict__ dst, int* __restrict__ count) {
    const int e = blockIdx.x * 256 + threadIdx.x;
    if (e < N_EDGES) atomicAdd(count + dst[e], 1);
}

__global__ __launch_bounds__(SCAN_B) void k_part(const int* __restrict__ count,
                                                 int* __restrict__ partial) {
    const int i = blockIdx.x * SCAN_B + threadIdx.x;
    int v = (i < N_NODES) ? count[i] : 0;
    const int lane = threadIdx.x & 63;
    const int w    = threadIdx.x >> 6;
    __shared__ int ws[SCAN_B / 64];
    #pragma unroll
    for (int o = 32; o > 0; o >>= 1) v += __shfl_down(v, o, 64);
    if (lane == 0) ws[w] = v;
    __syncthreads();
    if (threadIdx.x == 0) {
        int s = 0;
        #pragma unroll
        for (int k = 0; k < SCAN_B / 64; ++k) s += ws[k];
        partial[blockIdx.x] = s;
    }
}

__global__ __launch_bounds__(512) void k_scanp(const int* __restrict__ partial,
                                               int* __restrict__ blockoff,
                                               int* __restrict__ rowstart) {
    __shared__ int s[512];
    const int t = threadIdx.x;
    int v = (t < SCAN_G) ? partial[t] : 0;
    s[t] = v;
    __syncthreads();
    for (int o = 1; o < 512; o <<= 1) {
        int u = (t >= o) ? s[t - o] : 0;
        __syncthreads();
        s[t] += u;
        __syncthreads();
    }
    if (t < SCAN_G) blockoff[t] = (t == 0) ? 0 : s[t - 1];
    if (t == 0) rowstart[N_NODES] = s[511];
}

__global__ __launch_bounds__(SCAN_B) void k_apply(const int* __restrict__ count,
                                                  const int* __restrict__ blockoff,
                                                  int* __restrict__ rowstart) {
    __shared__ int s[SCAN_B];
    const int i = blockIdx.x * SCAN_B + threadIdx.x;
    const int t = threadIdx.x;
    const int v = (i < N_NODES) ? count[i] : 0;
    s[t] = v;
    __syncthreads();
    for (int o = 1; o < SCAN_B; o <<= 1) {
        int u = (t >= o) ? s[t - o] : 0;
        __syncthreads();
        s[t] += u;
        __syncthreads();
    }
    if (i < N_NODES) rowstart[i] = blockoff[blockIdx.x] + (s[t] - v);
}

// place edge into CSR slot; src_s stores src*HC (pre-scaled for the hot loop);
// if COPY, also copy the 64B eattr row into CSR order (replaces k_permea pass)
template<bool COPY>
__global__ void k_place(const int* __restrict__ src, const int* __restrict__ dst,
                        const int* __restrict__ rowstart, int* __restrict__ cursor,
                        int* __restrict__ perm, int* __restrict__ src_s,
                        const float* __restrict__ eattr, float* __restrict__ eattr_s) {
    const int e = blockIdx.x * 256 + threadIdx.x;
    if (e >= N_EDGES) return;
    const int d = dst[e];
    const int pos = rowstart[d] + atomicAdd(cursor + d, 1);
    src_s[pos] = src[e] * HC;
    if (COPY) {
        const float4* s4 = (const float4*)(eattr + (size_t)e * ED_DIM);
        float4* d4 = (float4*)(eattr_s + (size_t)pos * ED_DIM);
        d4[0] = s4[0]; d4[1] = s4[1]; d4[2] = s4[2]; d4[3] = s4[3];
    } else {
        perm[pos] = e;
    }
}

// ====== degree-bucket counting sort of nodes (descending degree) =============
__global__ __launch_bounds__(256) void k_deghist(const int* __restrict__ cnt,
                                                 int* __restrict__ dhist) {
    __shared__ int lh[DBIN];
    const int t = threadIdx.x;
    if (t < DBIN) lh[t] = 0;
    __syncthreads();
    const int n = blockIdx.x * 256 + t;
    if (n < N_NODES) atomicAdd(&lh[min(cnt[n], DBIN - 1)], 1);
    __syncthreads();
    if (t < DBIN && lh[t] > 0) atomicAdd(dhist + t, lh[t]);
}

// also zeroes the perm/src_s padding (ws is re-poisoned before every launch)
__global__ void k_degoff(const int* __restrict__ dhist, int* __restrict__ dcur,
                         int* __restrict__ perm, int* __restrict__ src_s) {
    if (threadIdx.x == 0) {
        int off = 0;
        for (int b = DBIN - 1; b >= 0; --b) { dcur[b] = off; off += dhist[b]; }
        for (int i = 0; i < EPAD; ++i) {
            perm[N_EDGES + i]  = 0;
            src_s[N_EDGES + i] = 0;
        }
    }
}

__global__ __launch_bounds__(256) void k_degplace(const int* __restrict__ cnt,
                                                  int* __restrict__ dcur,
                                                  int* __restrict__ nodeord) {
    __shared__ int lh[DBIN];
    __shared__ int base[DBIN];
    const int t = threadIdx.x;
    if (t < DBIN) lh[t] = 0;
    __syncthreads();
    const int n = blockIdx.x * 256 + t;
    int b = 0, r = 0;
    if (n < N_NODES) {
        b = min(cnt[n], DBIN - 1);
        r = atomicAdd(&lh[b], 1);
    }
    __syncthreads();
    if (t < DBIN && lh[t] > 0) base[t] = atomicAdd(dcur + t, lh[t]);
    __syncthreads();
    if (n < N_NODES) nodeord[base[b] + r] = n;
}

// ====== fused dual node transform: xl = A@WL^T+bL, xr = A@WR^T+bR ============
template<int DIN>
__global__ __launch_bounds__(320) void k_xform2(
    const float* __restrict__ A,
    const float* __restrict__ WL, const float* __restrict__ bL,
    const float* __restrict__ WR, const float* __restrict__ bR,
    float* __restrict__ outL, float* __restrict__ outR, int nn) {
    __shared__ float As[16][68];
    __shared__ float WsL[16][80];
    __shared__ float WsR[16][80];
    const int t  = threadIdx.x;
    const int n0 = blockIdx.x * 64;
    const int tn = (t & 15) * 4;
    const int tj = (t >> 4) * 4;
    float4 accL[4], accR[4];
    #pragma unroll
    for (int u = 0; u < 4; ++u) {
        accL[u] = make_float4(0.f, 0.f, 0.f, 0.f);
        accR[u] = make_float4(0.f, 0.f, 0.f, 0.f);
    }

    for (int k0 = 0; k0 < DIN; k0 += 16) {
        __syncthreads();
        for (int i = t; i < 64*16; i += 320) {
            int nl = i >> 4, kk = i & 15;
            int n = n0 + nl;
            As[kk][nl] = (n < nn) ? A[(size_t)n*DIN + k0 + kk] : 0.f;
        }
        for (int i = t; i < 80*16; i += 320) {
            int jj = i >> 4, kk = i & 15;
            WsL[kk][jj] = WL[(size_t)jj*DIN + k0 + kk];
            WsR[kk][jj] = WR[(size_t)jj*DIN + k0 + kk];
        }
        __syncthreads();
        #pragma unroll
        for (int k = 0; k < 16; ++k) {
            const float4 av = *(const float4*)&As[k][tn];
            const float4 wl = *(const float4*)&WsL[k][tj];
            const float4 wr = *(const float4*)&WsR[k][tj];
            accL[0].x += av.x*wl.x; accL[0].y += av.x*wl.y; accL[0].z += av.x*wl.z; accL[0].w += av.x*wl.w;
            accL[1].x += av.y*wl.x; accL[1].y += av.y*wl.y; accL[1].z += av.y*wl.z; accL[1].w += av.y*wl.w;
            accL[2].x += av.z*wl.x; accL[2].y += av.z*wl.y; accL[2].z += av.z*wl.z; accL[2].w += av.z*wl.w;
            accL[3].x += av.w*wl.x; accL[3].y += av.w*wl.y; accL[3].z += av.w*wl.z; accL[3].w += av.w*wl.w;
            accR[0].x += av.x*wr.x; accR[0].y += av.x*wr.y; accR[0].z += av.x*wr.z; accR[0].w += av.x*wr.w;
            accR[1].x += av.y*wr.x; accR[1].y += av.y*wr.y; accR[1].z += av.y*wr.z; accR[1].w += av.y*wr.w;
            accR[2].x += av.z*wr.x; accR[2].y += av.z*wr.y; accR[2].z += av.z*wr.z; accR[2].w += av.z*wr.w;
            accR[3].x += av.w*wr.x; accR[3].y += av.w*wr.y; accR[3].z += av.w*wr.z; accR[3].w += av.w*wr.w;
        }
    }
    const float4 bvL = *(const float4*)(bL + tj);
    const float4 bvR = *(const float4*)(bR + tj);
    #pragma unroll
    for (int u = 0; u < 4; ++u) {
        int n = n0 + tn + u;
        if (n < nn) {
            float4 o;
            o.x = accL[u].x + bvL.x; o.y = accL[u].y + bvL.y;
            o.z = accL[u].z + bvL.z; o.w = accL[u].w + bvL.w;
            *(float4*)(outL + (size_t)n*HC + tj) = o;
            o.x = accR[u].x + bvR.x; o.y = accR[u].y + bvR.y;
            o.z = accR[u].z + bvR.z; o.w = accR[u].w + bvR.w;
            *(float4*)(outR + (size_t)n*HC + tj) = o;
        }
    }
}

// DPP rotate within each 16-lane row: pure VALU cross-lane, no LDS pipe.
// row_ror:n -> lane i reads lane (i-n)&15 of its row (data rotates toward
// higher lanes; same convention as row_shr in the canonical DPP scan).
// ctrl: 0x121 = row_ror:1, 0x122 = row_ror:2, 0x124 = row_ror:4, 0x128 = row_ror:8
template<int CTRL>
__device__ __forceinline__ float dpp_ror(float v) {
    return __int_as_float(__builtin_amdgcn_update_dpp(
        0, __float_as_int(v), CTRL, 0xF, 0xF, true));
}

// per-edge logit+exp+accumulate. em via systolic rotate-accumulate:
// r starts as ea[c&15]; after s rotations lane i holds ea[(i-s)&15], which is
// multiplied by the pre-permuted weight wr[s] = we[c][(c-s)&15]. 15 mov_dpp +
// 16 FMA, zero LDS-pipe traffic. Head reduction via DPP rotate-adds.
__device__ __forceinline__ void edge_step_rot(
    float eav, float xlv, float xrc, float attc,
    const float (&wr)[16],
    float gate, float& acc, float& l) {
    float r = eav;
    float em = wr[0] * r;
    #pragma unroll
    for (int s = 1; s < 16; ++s) {
        r = dpp_ror<0x121>(r);
        em = __fmaf_rn(wr[s], r, em);
    }
    float v = xlv + xrc + em;
    v = fmaxf(v, 0.f) + NEG_SLOPE * fminf(v, 0.f);
    v *= attc;
    // full 16-lane-row sum, broadcast to all lanes (rotation group => exact)
    v += dpp_ror<0x121>(v);
    v += dpp_ror<0x122>(v);
    v += dpp_ror<0x124>(v);
    v += dpp_ror<0x128>(v);
    const float pt = __expf(v) * gate;
    acc += pt * xlv;
    l   += pt;
}

// ====== fused attention v7: 1 node per 80-thread group, 2 edges/iter ========
// thread = channel c (head = c>>4). Lane-sliced eattr (1 dword/thread/edge,
// prefetched one iteration ahead); em + head-reduce entirely on the VALU via
// DPP (no ds_swizzle -> LDS pipe idle). 2-edge unroll with 4-deep prefetch:
// all loads issued at iteration top, no intra-iteration dependent chains.
// src_s is pre-scaled by HC. Pads make all prefetches in-bounds; pad-driven
// garbage is bounded (exp finite) and killed by gate=0.
template<bool SORTED>
__global__ __launch_bounds__(320) void k_fused7(
    const float* __restrict__ xl, const float* __restrict__ xr,
    const float* __restrict__ ea,   // eattr_s if SORTED, raw eattr otherwise
    const float* __restrict__ we, const float* __restrict__ att,
    const int* __restrict__ perm, const int* __restrict__ src_s,
    const int* __restrict__ rowstart, const int* __restrict__ nodeord,
    const float* __restrict__ bias, float* __restrict__ out, int relu) {
    const int t = threadIdx.x;
    const int group = t / 80;
    const int c = t - group * 80;
    const int idx = blockIdx.x * 4 + group;
    if (idx >= N_NODES) return;
    const int n = nodeord[idx];

    // pre-permuted we row: wr[s] = we[c][(c-s)&15]
    float wr[16];
    #pragma unroll
    for (int s = 0; s < 16; ++s)
        wr[s] = we[c * ED_DIM + ((c - s) & 15)];
    const float attc = att[c];
    const float bc   = bias[c];
    const float xrc  = xr[n * HC + c];
    const int lane16 = c & 15;

    const int rs = rowstart[n], re = rowstart[n + 1];
    float l = 0.f, acc = 0.f;

    if (rs < re) {
        // preamble: values for p, p+1 in flight; src offsets for p+2, p+3
        const int o0 = src_s[rs];
        const int o1 = src_s[rs + 1];
        int sA = src_s[rs + 2];
        int sB = src_s[rs + 3];
        float xlA = xl[o0 + c];
        float xlB = xl[o1 + c];
        const int e0 = SORTED ? rs       : perm[rs];
        const int e1 = SORTED ? (rs + 1) : perm[rs + 1];
        float eaA = ea[e0 * ED_DIM + lane16];
        float eaB = ea[e1 * ED_DIM + lane16];

        for (int p = rs; p < re; p += 2) {
            const float xl0 = xlA, xl1 = xlB;
            const float ea0 = eaA, ea1 = eaB;
            // issue next loads (for p+2, p+3); no dependent chains in-iter
            xlA = xl[sA + c];
            xlB = xl[sB + c];
            sA = src_s[p + 4];
            sB = src_s[p + 5];
            const int en0 = SORTED ? (p + 2) : perm[p + 2];
            const int en1 = SORTED ? (p + 3) : perm[p + 3];
            eaA = ea[en0 * ED_DIM + lane16];
            eaB = ea[en1 * ED_DIM + lane16];

            edge_step_rot(ea0, xl0, xrc, attc, wr, 1.f, acc, l);
            const float g1 = (p + 1 < re) ? 1.f : 0.f;
            edge_step_rot(ea1, xl1, xrc, attc, wr, g1, acc, l);
        }
    }
    float o = acc / (l + 1e-16f) + bc;
    if (relu) o = fmaxf(o, 0.f);
    out[n * HC + c] = o;
}

extern "C" void kernel_launch(void* const* d_in, const int* in_sizes, int n_in,
                              void* d_out, int out_size, void* d_ws, size_t ws_size,
                              hipStream_t stream) {
    (void)in_sizes; (void)n_in; (void)out_size;
    const float* x     = (const float*)d_in[0];
    const int*   ei    = (const int*)d_in[1];
    const float* eattr = (const float*)d_in[2];
    const int* srcp = ei;
    const int* dstp = ei + N_EDGES;

    // workspace layout
    float* h      = (float*)d_ws;                            // N*80
    float* xl     = h  + (size_t)N_NODES*HC;                 // N*80
    float* xr     = xl + (size_t)N_NODES*HC;                 // N*80
    int* rowstart = (int*)(xr + (size_t)N_NODES*HC);         // N+1
    int* cursor   = rowstart + (N_NODES + 1);                // N
    int* perm     = cursor + N_NODES;                        // E + EPAD
    int* src_s    = perm + N_EDGES + EPAD;                   // E + EPAD
    int* partial  = src_s + N_EDGES + EPAD;                  // SCAN_G
    int* blockoff = partial + SCAN_G;                        // SCAN_G
    int* dhist    = blockoff + SCAN_G;                       // DBIN
    int* dcur     = dhist + DBIN;                            // DBIN
    int* nodeord  = dcur + DBIN;                             // N
    // 64B-align eattr_s (rows are written with dwordx4 in k_place)
    float* eattr_s = (float*)(((uintptr_t)(nodeord + N_NODES) + 63) &
                              ~(uintptr_t)63);               // (E+8)*16 (optional)
    float* outp   = (float*)d_out;

    const size_t need_sorted =
        (size_t)((char*)(eattr_s + (size_t)(N_EDGES + EPAD) * ED_DIM) - (char*)d_ws);
    const bool use_sorted = (ws_size >= need_sorted);

    const dim3 bx(320);
    const dim3 gx((N_NODES + 63) / 64);
    const dim3 gf((N_NODES + 3) / 4);
    const dim3 geb((N_EDGES + 255) / 256);
    const dim3 gnb((N_NODES + 255) / 256);

    // ---- build CSR by destination + degree-sorted node order (once) ----
    hipMemsetAsync(cursor, 0, (size_t)N_NODES * sizeof(int), stream);
    hipMemsetAsync(dhist, 0, DBIN * sizeof(int), stream);
    k_hist<<<geb, 256, 0, stream>>>(dstp, cursor);
    k_part<<<SCAN_G, SCAN_B, 0, stream>>>(cursor, partial);
    k_scanp<<<1, 512, 0, stream>>>(partial, blockoff, rowstart);
    k_apply<<<SCAN_G, SCAN_B, 0, stream>>>(cursor, blockoff, rowstart);
    k_deghist<<<gnb, 256, 0, stream>>>(cursor, dhist);
    k_degoff<<<1, 64, 0, stream>>>(dhist, dcur, perm, src_s);
    k_degplace<<<gnb, 256, 0, stream>>>(cursor, dcur, nodeord);
    hipMemsetAsync(cursor, 0, (size_t)N_NODES * sizeof(int), stream);
    if (use_sorted) {
        k_place<true><<<geb, 256, 0, stream>>>(srcp, dstp, rowstart, cursor,
                                               perm, src_s, eattr, eattr_s);
    } else {
        k_place<false><<<geb, 256, 0, stream>>>(srcp, dstp, rowstart, cursor,
                                                perm, src_s, eattr, eattr_s);
    }

    for (int L = 0; L < 3; ++L) {
        const float* in   = (L == 0) ? x : h;
        float*       oacc = (L == 2) ? outp : h;
        const float* wl   = (const float*)d_in[3 + L*7 + 0];
        const float* bl   = (const float*)d_in[3 + L*7 + 1];
        const float* wr   = (const float*)d_in[3 + L*7 + 2];
        const float* br   = (const float*)d_in[3 + L*7 + 3];
        const float* we   = (const float*)d_in[3 + L*7 + 4];
        const float* att  = (const float*)d_in[3 + L*7 + 5];
        const float* bias = (const float*)d_in[3 + L*7 + 6];

        if (L == 0) {
            k_xform2<F_IN><<<gx, bx, 0, stream>>>(in, wl, bl, wr, br, xl, xr, N_NODES);
        } else {
            k_xform2<HC><<<gx, bx, 0, stream>>>(in, wl, bl, wr, br, xl, xr, N_NODES);
        }
        if (use_sorted) {
            k_fused7<true><<<gf, bx, 0, stream>>>(xl, xr, eattr_s, we, att, perm,
                                                  src_s, rowstart, nodeord, bias,
                                                  oacc, (L < 2) ? 1 : 0);
        } else {
            k_fused7<false><<<gf, bx, 0, stream>>>(xl, xr, eattr, we, att, perm,
                                                   src_s, rowstart, nodeord, bias,
                                                   oacc, (L < 2) ? 1 : 0);
        }
    }
}

// Round 3
// 967.521 us; speedup vs baseline: 1.2092x; 1.0432x over previous
//
#include <hip/hip_runtime.h>
#include <hip/hip_bf16.h>
#include <math.h>
#include <stdint.h>

#define N_NODES 100000
#define N_EDGES 1000000
#define F_IN    128
#define ED_DIM  16
#define H_HEADS 5
#define C_CH    16
#define HC      80
#define NEG_SLOPE 0.2f

#define SCAN_B 256
#define SCAN_G ((N_NODES + SCAN_B - 1) / SCAN_B)   // 391
#define DBIN 64
#define EPAD 8   // padding entries on src_s/perm; 8 pad rows on eattr_s

// ================= CSR build (graph is static across layers) =================

__global__ void k_hist(const int* __restrict__ dst, int* __restrict__ count) {
    const int e = blockIdx.x * 256 + threadIdx.x;
    if (e < N_EDGES) atomicAdd(count + dst[e], 1);
}

__global__ __launch_bounds__(SCAN_B) void k_part(const int* __restrict__ count,
                                                 int* __restrict__ partial) {
    const int i = blockIdx.x * SCAN_B + threadIdx.x;
    int v = (i < N_NODES) ? count[i] : 0;
    const int lane = threadIdx.x & 63;
    const int w    = threadIdx.x >> 6;
    __shared__ int ws[SCAN_B / 64];
    #pragma unroll
    for (int o = 32; o > 0; o >>= 1) v += __shfl_down(v, o, 64);
    if (lane == 0) ws[w] = v;
    __syncthreads();
    if (threadIdx.x == 0) {
        int s = 0;
        #pragma unroll
        for (int k = 0; k < SCAN_B / 64; ++k) s += ws[k];
        partial[blockIdx.x] = s;
    }
}

__global__ __launch_bounds__(512) void k_scanp(const int* __restrict__ partial,
                                               int* __restrict__ blockoff,
                                               int* __restrict__ rowstart) {
    __shared__ int s[512];
    const int t = threadIdx.x;
    int v = (t < SCAN_G) ? partial[t] : 0;
    s[t] = v;
    __syncthreads();
    for (int o = 1; o < 512; o <<= 1) {
        int u = (t >= o) ? s[t - o] : 0;
        __syncthreads();
        s[t] += u;
        __syncthreads();
    }
    if (t < SCAN_G) blockoff[t] = (t == 0) ? 0 : s[t - 1];
    if (t == 0) rowstart[N_NODES] = s[511];
}

__global__ __launch_bounds__(SCAN_B) void k_apply(const int* __restrict__ count,
                                                  const int* __restrict__ blockoff,
                                                  int* __restrict__ rowstart) {
    __shared__ int s[SCAN_B];
    const int i = blockIdx.x * SCAN_B + threadIdx.x;
    const int t = threadIdx.x;
    const int v = (i < N_NODES) ? count[i] : 0;
    s[t] = v;
    __syncthreads();
    for (int o = 1; o < SCAN_B; o <<= 1) {
        int u = (t >= o) ? s[t - o] : 0;
        __syncthreads();
        s[t] += u;
        __syncthreads();
    }
    if (i < N_NODES) rowstart[i] = blockoff[blockIdx.x] + (s[t] - v);
}

// place edge into CSR slot; src_s stores src*HC (pre-scaled for the hot loop);
// if COPY, also copy the 64B eattr row into CSR order (replaces k_permea pass)
template<bool COPY>
__global__ void k_place(const int* __restrict__ src, const int* __restrict__ dst,
                        const int* __restrict__ rowstart, int* __restrict__ cursor,
                        int* __restrict__ perm, int* __restrict__ src_s,
                        const float* __restrict__ eattr, float* __restrict__ eattr_s) {
    const int e = blockIdx.x * 256 + threadIdx.x;
    if (e >= N_EDGES) return;
    const int d = dst[e];
    const int pos = rowstart[d] + atomicAdd(cursor + d, 1);
    src_s[pos] = src[e] * HC;
    if (COPY) {
        const float4* s4 = (const float4*)(eattr + (size_t)e * ED_DIM);
        float4* d4 = (float4*)(eattr_s + (size_t)pos * ED_DIM);
        d4[0] = s4[0]; d4[1] = s4[1]; d4[2] = s4[2]; d4[3] = s4[3];
    } else {
        perm[pos] = e;
    }
}

// ====== degree-bucket counting sort of nodes (descending degree) =============
__global__ __launch_bounds__(256) void k_deghist(const int* __restrict__ cnt,
                                                 int* __restrict__ dhist) {
    __shared__ int lh[DBIN];
    const int t = threadIdx.x;
    if (t < DBIN) lh[t] = 0;
    __syncthreads();
    const int n = blockIdx.x * 256 + t;
    if (n < N_NODES) atomicAdd(&lh[min(cnt[n], DBIN - 1)], 1);
    __syncthreads();
    if (t < DBIN && lh[t] > 0) atomicAdd(dhist + t, lh[t]);
}

// also zeroes the perm/src_s padding (ws is re-poisoned before every launch)
__global__ void k_degoff(const int* __restrict__ dhist, int* __restrict__ dcur,
                         int* __restrict__ perm, int* __restrict__ src_s) {
    if (threadIdx.x == 0) {
        int off = 0;
        for (int b = DBIN - 1; b >= 0; --b) { dcur[b] = off; off += dhist[b]; }
        for (int i = 0; i < EPAD; ++i) {
            perm[N_EDGES + i]  = 0;
            src_s[N_EDGES + i] = 0;
        }
    }
}

__global__ __launch_bounds__(256) void k_degplace(const int* __restrict__ cnt,
                                                  int* __restrict__ dcur,
                                                  int* __restrict__ nodeord) {
    __shared__ int lh[DBIN];
    __shared__ int base[DBIN];
    const int t = threadIdx.x;
    if (t < DBIN) lh[t] = 0;
    __syncthreads();
    const int n = blockIdx.x * 256 + t;
    int b = 0, r = 0;
    if (n < N_NODES) {
        b = min(cnt[n], DBIN - 1);
        r = atomicAdd(&lh[b], 1);
    }
    __syncthreads();
    if (t < DBIN && lh[t] > 0) base[t] = atomicAdd(dcur + t, lh[t]);
    __syncthreads();
    if (n < N_NODES) nodeord[base[b] + r] = n;
}

// ====== fused dual node transform: xl = A@WL^T+bL, xr = A@WR^T+bR ============
template<int DIN>
__global__ __launch_bounds__(320) void k_xform2(
    const float* __restrict__ A,
    const float* __restrict__ WL, const float* __restrict__ bL,
    const float* __restrict__ WR, const float* __restrict__ bR,
    float* __restrict__ outL, float* __restrict__ outR, int nn) {
    __shared__ float As[16][68];
    __shared__ float WsL[16][80];
    __shared__ float WsR[16][80];
    const int t  = threadIdx.x;
    const int n0 = blockIdx.x * 64;
    const int tn = (t & 15) * 4;
    const int tj = (t >> 4) * 4;
    float4 accL[4], accR[4];
    #pragma unroll
    for (int u = 0; u < 4; ++u) {
        accL[u] = make_float4(0.f, 0.f, 0.f, 0.f);
        accR[u] = make_float4(0.f, 0.f, 0.f, 0.f);
    }

    for (int k0 = 0; k0 < DIN; k0 += 16) {
        __syncthreads();
        for (int i = t; i < 64*16; i += 320) {
            int nl = i >> 4, kk = i & 15;
            int n = n0 + nl;
            As[kk][nl] = (n < nn) ? A[(size_t)n*DIN + k0 + kk] : 0.f;
        }
        for (int i = t; i < 80*16; i += 320) {
            int jj = i >> 4, kk = i & 15;
            WsL[kk][jj] = WL[(size_t)jj*DIN + k0 + kk];
            WsR[kk][jj] = WR[(size_t)jj*DIN + k0 + kk];
        }
        __syncthreads();
        #pragma unroll
        for (int k = 0; k < 16; ++k) {
            const float4 av = *(const float4*)&As[k][tn];
            const float4 wl = *(const float4*)&WsL[k][tj];
            const float4 wr = *(const float4*)&WsR[k][tj];
            accL[0].x += av.x*wl.x; accL[0].y += av.x*wl.y; accL[0].z += av.x*wl.z; accL[0].w += av.x*wl.w;
            accL[1].x += av.y*wl.x; accL[1].y += av.y*wl.y; accL[1].z += av.y*wl.z; accL[1].w += av.y*wl.w;
            accL[2].x += av.z*wl.x; accL[2].y += av.z*wl.y; accL[2].z += av.z*wl.z; accL[2].w += av.z*wl.w;
            accL[3].x += av.w*wl.x; accL[3].y += av.w*wl.y; accL[3].z += av.w*wl.z; accL[3].w += av.w*wl.w;
            accR[0].x += av.x*wr.x; accR[0].y += av.x*wr.y; accR[0].z += av.x*wr.z; accR[0].w += av.x*wr.w;
            accR[1].x += av.y*wr.x; accR[1].y += av.y*wr.y; accR[1].z += av.y*wr.z; accR[1].w += av.y*wr.w;
            accR[2].x += av.z*wr.x; accR[2].y += av.z*wr.y; accR[2].z += av.z*wr.z; accR[2].w += av.z*wr.w;
            accR[3].x += av.w*wr.x; accR[3].y += av.w*wr.y; accR[3].z += av.w*wr.z; accR[3].w += av.w*wr.w;
        }
    }
    const float4 bvL = *(const float4*)(bL + tj);
    const float4 bvR = *(const float4*)(bR + tj);
    #pragma unroll
    for (int u = 0; u < 4; ++u) {
        int n = n0 + tn + u;
        if (n < nn) {
            float4 o;
            o.x = accL[u].x + bvL.x; o.y = accL[u].y + bvL.y;
            o.z = accL[u].z + bvL.z; o.w = accL[u].w + bvL.w;
            *(float4*)(outL + (size_t)n*HC + tj) = o;
            o.x = accR[u].x + bvR.x; o.y = accR[u].y + bvR.y;
            o.z = accR[u].z + bvR.z; o.w = accR[u].w + bvR.w;
            *(float4*)(outR + (size_t)n*HC + tj) = o;
        }
    }
}

// cross-lane helpers.
// BC: compile-time ds_swizzle broadcast (DS pipe, latency-parallel):
//   imm = (j<<5)|0x10 -> lane i reads lane (i&0x10)|j within each 32-lane
//   group, i.e. each 16-lane row gets element j of its own copy of ea.
#define SWZ(v, imm) __int_as_float(__builtin_amdgcn_ds_swizzle(__float_as_int(v), (imm)))
#define BC(v, j) SWZ(v, ((j) << 5) | 0x10)

// DPP rotate within each 16-lane row: pure VALU cross-lane, short latency.
// ctrl: 0x121 = row_ror:1, 0x122 = row_ror:2, 0x124 = row_ror:4, 0x128 = row_ror:8
template<int CTRL>
__device__ __forceinline__ float dpp_ror(float v) {
    return __int_as_float(__builtin_amdgcn_update_dpp(
        0, __float_as_int(v), CTRL, 0xF, 0xF, true));
}

// per-edge logit+exp+accumulate — hybrid pipe split:
//   em broadcasts on the DS pipe (16 independent ds_swizzle, per-CU pipe),
//   head reduction on the VALU via 4 short-latency DPP rotate-adds.
__device__ __forceinline__ void edge_step8(
    float eav, float xlv, float xrc, float attc,
    const float4& w0, const float4& w1, const float4& w2, const float4& w3,
    float gate, float& acc, float& l) {
    float m0 = w0.x * BC(eav, 0)  + w0.y * BC(eav, 1)
             + w0.z * BC(eav, 2)  + w0.w * BC(eav, 3);
    float m1 = w1.x * BC(eav, 4)  + w1.y * BC(eav, 5)
             + w1.z * BC(eav, 6)  + w1.w * BC(eav, 7);
    float m2 = w2.x * BC(eav, 8)  + w2.y * BC(eav, 9)
             + w2.z * BC(eav, 10) + w2.w * BC(eav, 11);
    float m3 = w3.x * BC(eav, 12) + w3.y * BC(eav, 13)
             + w3.z * BC(eav, 14) + w3.w * BC(eav, 15);
    float v = (xlv + xrc) + ((m0 + m1) + (m2 + m3));
    v = fmaxf(v, 0.f) + NEG_SLOPE * fminf(v, 0.f);
    v *= attc;
    // full 16-lane-row sum, broadcast to all lanes (rotation group => exact)
    v += dpp_ror<0x121>(v);
    v += dpp_ror<0x122>(v);
    v += dpp_ror<0x124>(v);
    v += dpp_ror<0x128>(v);
    const float pt = __expf(v) * gate;
    acc += pt * xlv;
    l   += pt;
}

// ====== fused attention v8: 1 node per 80-thread group, 2 edges/iter ========
// thread = channel c (head = c>>4). Lane-sliced eattr; em via immediate
// ds_swizzle broadcasts (DS pipe); head-reduce via DPP rotate-adds (VALU,
// replaces the 4-deep ~150-cycle ds_swizzle butterfly chain of v5).
// 2-edge unroll with 4-deep prefetch pipeline: all loads issued at iteration
// top, no intra-iteration dependent chains. src_s is pre-scaled by HC. Pads
// make all prefetches in-bounds; pad-driven garbage is bounded (exp finite)
// and killed by gate=0.
template<bool SORTED>
__global__ __launch_bounds__(320) void k_fused8(
    const float* __restrict__ xl, const float* __restrict__ xr,
    const float* __restrict__ ea,   // eattr_s if SORTED, raw eattr otherwise
    const float* __restrict__ we, const float* __restrict__ att,
    const int* __restrict__ perm, const int* __restrict__ src_s,
    const int* __restrict__ rowstart, const int* __restrict__ nodeord,
    const float* __restrict__ bias, float* __restrict__ out, int relu) {
    const int t = threadIdx.x;
    const int group = t / 80;
    const int c = t - group * 80;
    const int idx = blockIdx.x * 4 + group;
    if (idx >= N_NODES) return;
    const int n = nodeord[idx];

    const float4* w4 = (const float4*)(we + c * ED_DIM);
    const float4 w0 = w4[0], w1 = w4[1], w2 = w4[2], w3 = w4[3];
    const float attc = att[c];
    const float bc   = bias[c];
    const float xrc  = xr[n * HC + c];
    const int lane16 = c & 15;

    const int rs = rowstart[n], re = rowstart[n + 1];
    float l = 0.f, acc = 0.f;

    if (rs < re) {
        // preamble: values for p, p+1 in flight; src offsets for p+2, p+3
        const int o0 = src_s[rs];
        const int o1 = src_s[rs + 1];
        int sA = src_s[rs + 2];
        int sB = src_s[rs + 3];
        float xlA = xl[o0 + c];
        float xlB = xl[o1 + c];
        const int e0 = SORTED ? rs       : perm[rs];
        const int e1 = SORTED ? (rs + 1) : perm[rs + 1];
        float eaA = ea[e0 * ED_DIM + lane16];
        float eaB = ea[e1 * ED_DIM + lane16];

        for (int p = rs; p < re; p += 2) {
            const float xl0 = xlA, xl1 = xlB;
            const float ea0 = eaA, ea1 = eaB;
            // issue next loads (for p+2, p+3); no dependent chains in-iter
            xlA = xl[sA + c];
            xlB = xl[sB + c];
            sA = src_s[p + 4];
            sB = src_s[p + 5];
            const int en0 = SORTED ? (p + 2) : perm[p + 2];
            const int en1 = SORTED ? (p + 3) : perm[p + 3];
            eaA = ea[en0 * ED_DIM + lane16];
            eaB = ea[en1 * ED_DIM + lane16];

            edge_step8(ea0, xl0, xrc, attc, w0, w1, w2, w3, 1.f, acc, l);
            const float g1 = (p + 1 < re) ? 1.f : 0.f;
            edge_step8(ea1, xl1, xrc, attc, w0, w1, w2, w3, g1, acc, l);
        }
    }
    float o = acc / (l + 1e-16f) + bc;
    if (relu) o = fmaxf(o, 0.f);
    out[n * HC + c] = o;
}

extern "C" void kernel_launch(void* const* d_in, const int* in_sizes, int n_in,
                              void* d_out, int out_size, void* d_ws, size_t ws_size,
                              hipStream_t stream) {
    (void)in_sizes; (void)n_in; (void)out_size;
    const float* x     = (const float*)d_in[0];
    const int*   ei    = (const int*)d_in[1];
    const float* eattr = (const float*)d_in[2];
    const int* srcp = ei;
    const int* dstp = ei + N_EDGES;

    // workspace layout
    float* h      = (float*)d_ws;                            // N*80
    float* xl     = h  + (size_t)N_NODES*HC;                 // N*80
    float* xr     = xl + (size_t)N_NODES*HC;                 // N*80
    int* rowstart = (int*)(xr + (size_t)N_NODES*HC);         // N+1
    int* cursor   = rowstart + (N_NODES + 1);                // N
    int* perm     = cursor + N_NODES;                        // E + EPAD
    int* src_s    = perm + N_EDGES + EPAD;                   // E + EPAD
    int* partial  = src_s + N_EDGES + EPAD;                  // SCAN_G
    int* blockoff = partial + SCAN_G;                        // SCAN_G
    int* dhist    = blockoff + SCAN_G;                       // DBIN
    int* dcur     = dhist + DBIN;                            // DBIN
    int* nodeord  = dcur + DBIN;                             // N
    // 64B-align eattr_s (rows are written with dwordx4 in k_place)
    float* eattr_s = (float*)(((uintptr_t)(nodeord + N_NODES) + 63) &
                              ~(uintptr_t)63);               // (E+8)*16 (optional)
    float* outp   = (float*)d_out;

    const size_t need_sorted =
        (size_t)((char*)(eattr_s + (size_t)(N_EDGES + EPAD) * ED_DIM) - (char*)d_ws);
    const bool use_sorted = (ws_size >= need_sorted);

    const dim3 bx(320);
    const dim3 gx((N_NODES + 63) / 64);
    const dim3 gf((N_NODES + 3) / 4);
    const dim3 geb((N_EDGES + 255) / 256);
    const dim3 gnb((N_NODES + 255) / 256);

    // ---- build CSR by destination + degree-sorted node order (once) ----
    hipMemsetAsync(cursor, 0, (size_t)N_NODES * sizeof(int), stream);
    hipMemsetAsync(dhist, 0, DBIN * sizeof(int), stream);
    k_hist<<<geb, 256, 0, stream>>>(dstp, cursor);
    k_part<<<SCAN_G, SCAN_B, 0, stream>>>(cursor, partial);
    k_scanp<<<1, 512, 0, stream>>>(partial, blockoff, rowstart);
    k_apply<<<SCAN_G, SCAN_B, 0, stream>>>(cursor, blockoff, rowstart);
    k_deghist<<<gnb, 256, 0, stream>>>(cursor, dhist);
    k_degoff<<<1, 64, 0, stream>>>(dhist, dcur, perm, src_s);
    k_degplace<<<gnb, 256, 0, stream>>>(cursor, dcur, nodeord);
    hipMemsetAsync(cursor, 0, (size_t)N_NODES * sizeof(int), stream);
    if (use_sorted) {
        k_place<true><<<geb, 256, 0, stream>>>(srcp, dstp, rowstart, cursor,
                                               perm, src_s, eattr, eattr_s);
    } else {
        k_place<false><<<geb, 256, 0, stream>>>(srcp, dstp, rowstart, cursor,
                                                perm, src_s, eattr, eattr_s);
    }

    for (int L = 0; L < 3; ++L) {
        const float* in   = (L == 0) ? x : h;
        float*       oacc = (L == 2) ? outp : h;
        const float* wl   = (const float*)d_in[3 + L*7 + 0];
        const float* bl   = (const float*)d_in[3 + L*7 + 1];
        const float* wr   = (const float*)d_in[3 + L*7 + 2];
        const float* br   = (const float*)d_in[3 + L*7 + 3];
        const float* we   = (const float*)d_in[3 + L*7 + 4];
        const float* att  = (const float*)d_in[3 + L*7 + 5];
        const float* bias = (const float*)d_in[3 + L*7 + 6];

        if (L == 0) {
            k_xform2<F_IN><<<gx, bx, 0, stream>>>(in, wl, bl, wr, br, xl, xr, N_NODES);
        } else {
            k_xform2<HC><<<gx, bx, 0, stream>>>(in, wl, bl, wr, br, xl, xr, N_NODES);
        }
        if (use_sorted) {
            k_fused8<true><<<gf, bx, 0, stream>>>(xl, xr, eattr_s, we, att, perm,
                                                  src_s, rowstart, nodeord, bias,
                                                  oacc, (L < 2) ? 1 : 0);
        } else {
            k_fused8<false><<<gf, bx, 0, stream>>>(xl, xr, eattr, we, att, perm,
                                                   src_s, rowstart, nodeord, bias,
                                                   oacc, (L < 2) ? 1 : 0);
        }
    }
}

// Round 5
// 885.584 us; speedup vs baseline: 1.3211x; 1.0925x over previous
//
#include <hip/hip_runtime.h>
#include <math.h>
#include <stdint.h>

#define N_NODES 100000
#define N_EDGES 1000000
#define F_IN    128
#define ED_DIM  16
#define H_HEADS 5
#define C_CH    16
#define HC      80
#define NEG_SLOPE 0.2f

#define SCAN_B 256
#define SCAN_G ((N_NODES + SCAN_B - 1) / SCAN_B)   // 391
#define DBIN 64
#define EPAD 8   // padding entries on src_s/perm; 8 pad rows on eattr_s

typedef _Float16 h2 __attribute__((ext_vector_type(2)));

#if __has_builtin(__builtin_amdgcn_fdot2)
#define FDOT2(a, b, c) __builtin_amdgcn_fdot2((a), (b), (c), false)
#else
__device__ __forceinline__ float FDOT2(h2 a, h2 b, float c) {
    return (float)a.x * (float)b.x + (float)a.y * (float)b.y + c;
}
#endif

// cvt_pkrtz returns a __fp16-vector on this clang; bit_cast to our h2
#define PKH2(x, y) __builtin_bit_cast(h2, __builtin_amdgcn_cvt_pkrtz((x), (y)))

// ================= CSR build (graph is static across layers) =================

__global__ void k_hist(const int* __restrict__ dst, int* __restrict__ count) {
    const int e = blockIdx.x * 256 + threadIdx.x;
    if (e < N_EDGES) atomicAdd(count + dst[e], 1);
}

__global__ __launch_bounds__(SCAN_B) void k_part(const int* __restrict__ count,
                                                 int* __restrict__ partial) {
    const int i = blockIdx.x * SCAN_B + threadIdx.x;
    int v = (i < N_NODES) ? count[i] : 0;
    const int lane = threadIdx.x & 63;
    const int w    = threadIdx.x >> 6;
    __shared__ int ws[SCAN_B / 64];
    #pragma unroll
    for (int o = 32; o > 0; o >>= 1) v += __shfl_down(v, o, 64);
    if (lane == 0) ws[w] = v;
    __syncthreads();
    if (threadIdx.x == 0) {
        int s = 0;
        #pragma unroll
        for (int k = 0; k < SCAN_B / 64; ++k) s += ws[k];
        partial[blockIdx.x] = s;
    }
}

__global__ __launch_bounds__(512) void k_scanp(const int* __restrict__ partial,
                                               int* __restrict__ blockoff,
                                               int* __restrict__ rowstart) {
    __shared__ int s[512];
    const int t = threadIdx.x;
    int v = (t < SCAN_G) ? partial[t] : 0;
    s[t] = v;
    __syncthreads();
    for (int o = 1; o < 512; o <<= 1) {
        int u = (t >= o) ? s[t - o] : 0;
        __syncthreads();
        s[t] += u;
        __syncthreads();
    }
    if (t < SCAN_G) blockoff[t] = (t == 0) ? 0 : s[t - 1];
    if (t == 0) rowstart[N_NODES] = s[511];
}

__global__ __launch_bounds__(SCAN_B) void k_apply(const int* __restrict__ count,
                                                  const int* __restrict__ blockoff,
                                                  int* __restrict__ rowstart) {
    __shared__ int s[SCAN_B];
    const int i = blockIdx.x * SCAN_B + threadIdx.x;
    const int t = threadIdx.x;
    const int v = (i < N_NODES) ? count[i] : 0;
    s[t] = v;
    __syncthreads();
    for (int o = 1; o < SCAN_B; o <<= 1) {
        int u = (t >= o) ? s[t - o] : 0;
        __syncthreads();
        s[t] += u;
        __syncthreads();
    }
    if (i < N_NODES) rowstart[i] = blockoff[blockIdx.x] + (s[t] - v);
}

// place edge into CSR slot; src_s stores src*HC (pre-scaled for the hot loop);
// if COPY, also convert+copy the eattr row into CSR order as 16 f16 (32B),
// packed as 8 half2 words. Pad rows (N_EDGES..N_EDGES+EPAD) are zeroed so
// prefetch overshoot yields exp(finite) killed by gate=0 (no inf*0 NaN).
template<bool COPY>
__global__ void k_place(const int* __restrict__ src, const int* __restrict__ dst,
                        const int* __restrict__ rowstart, int* __restrict__ cursor,
                        int* __restrict__ perm, int* __restrict__ src_s,
                        const float* __restrict__ eattr, int* __restrict__ eattr_h) {
    const int e = blockIdx.x * 256 + threadIdx.x;
    if (e >= N_EDGES) return;
    const int d = dst[e];
    const int pos = rowstart[d] + atomicAdd(cursor + d, 1);
    src_s[pos] = src[e] * HC;
    if (COPY) {
        const float4* s4 = (const float4*)(eattr + (size_t)e * ED_DIM);
        const float4 r0 = s4[0], r1 = s4[1], r2 = s4[2], r3 = s4[3];
        int4* d4 = (int4*)(eattr_h + (size_t)pos * 8);
        d4[0] = make_int4(__builtin_bit_cast(int, PKH2(r0.x, r0.y)),
                          __builtin_bit_cast(int, PKH2(r0.z, r0.w)),
                          __builtin_bit_cast(int, PKH2(r1.x, r1.y)),
                          __builtin_bit_cast(int, PKH2(r1.z, r1.w)));
        d4[1] = make_int4(__builtin_bit_cast(int, PKH2(r2.x, r2.y)),
                          __builtin_bit_cast(int, PKH2(r2.z, r2.w)),
                          __builtin_bit_cast(int, PKH2(r3.x, r3.y)),
                          __builtin_bit_cast(int, PKH2(r3.z, r3.w)));
        if (e < EPAD) {   // zero pad row N_EDGES+e (never hit by the scatter)
            int4* p4 = (int4*)(eattr_h + (size_t)(N_EDGES + e) * 8);
            p4[0] = make_int4(0, 0, 0, 0);
            p4[1] = make_int4(0, 0, 0, 0);
        }
    } else {
        perm[pos] = e;
    }
}

// ====== degree-bucket counting sort of nodes (descending degree) =============
__global__ __launch_bounds__(256) void k_deghist(const int* __restrict__ cnt,
                                                 int* __restrict__ dhist) {
    __shared__ int lh[DBIN];
    const int t = threadIdx.x;
    if (t < DBIN) lh[t] = 0;
    __syncthreads();
    const int n = blockIdx.x * 256 + t;
    if (n < N_NODES) atomicAdd(&lh[min(cnt[n], DBIN - 1)], 1);
    __syncthreads();
    if (t < DBIN && lh[t] > 0) atomicAdd(dhist + t, lh[t]);
}

// also zeroes the perm/src_s padding (ws is re-poisoned before every launch)
__global__ void k_degoff(const int* __restrict__ dhist, int* __restrict__ dcur,
                         int* __restrict__ perm, int* __restrict__ src_s) {
    if (threadIdx.x == 0) {
        int off = 0;
        for (int b = DBIN - 1; b >= 0; --b) { dcur[b] = off; off += dhist[b]; }
        for (int i = 0; i < EPAD; ++i) {
            perm[N_EDGES + i]  = 0;
            src_s[N_EDGES + i] = 0;
        }
    }
}

__global__ __launch_bounds__(256) void k_degplace(const int* __restrict__ cnt,
                                                  int* __restrict__ dcur,
                                                  int* __restrict__ nodeord) {
    __shared__ int lh[DBIN];
    __shared__ int base[DBIN];
    const int t = threadIdx.x;
    if (t < DBIN) lh[t] = 0;
    __syncthreads();
    const int n = blockIdx.x * 256 + t;
    int b = 0, r = 0;
    if (n < N_NODES) {
        b = min(cnt[n], DBIN - 1);
        r = atomicAdd(&lh[b], 1);
    }
    __syncthreads();
    if (t < DBIN && lh[t] > 0) base[t] = atomicAdd(dcur + t, lh[t]);
    __syncthreads();
    if (n < N_NODES) nodeord[base[b] + r] = n;
}

// ====== fused dual node transform: xl = A@WL^T+bL, xr = A@WR^T+bR ============
template<int DIN>
__global__ __launch_bounds__(320) void k_xform2(
    const float* __restrict__ A,
    const float* __restrict__ WL, const float* __restrict__ bL,
    const float* __restrict__ WR, const float* __restrict__ bR,
    float* __restrict__ outL, float* __restrict__ outR, int nn) {
    __shared__ float As[16][68];
    __shared__ float WsL[16][80];
    __shared__ float WsR[16][80];
    const int t  = threadIdx.x;
    const int n0 = blockIdx.x * 64;
    const int tn = (t & 15) * 4;
    const int tj = (t >> 4) * 4;
    float4 accL[4], accR[4];
    #pragma unroll
    for (int u = 0; u < 4; ++u) {
        accL[u] = make_float4(0.f, 0.f, 0.f, 0.f);
        accR[u] = make_float4(0.f, 0.f, 0.f, 0.f);
    }

    for (int k0 = 0; k0 < DIN; k0 += 16) {
        __syncthreads();
        for (int i = t; i < 64*16; i += 320) {
            int nl = i >> 4, kk = i & 15;
            int n = n0 + nl;
            As[kk][nl] = (n < nn) ? A[(size_t)n*DIN + k0 + kk] : 0.f;
        }
        for (int i = t; i < 80*16; i += 320) {
            int jj = i >> 4, kk = i & 15;
            WsL[kk][jj] = WL[(size_t)jj*DIN + k0 + kk];
            WsR[kk][jj] = WR[(size_t)jj*DIN + k0 + kk];
        }
        __syncthreads();
        #pragma unroll
        for (int k = 0; k < 16; ++k) {
            const float4 av = *(const float4*)&As[k][tn];
            const float4 wl = *(const float4*)&WsL[k][tj];
            const float4 wr = *(const float4*)&WsR[k][tj];
            accL[0].x += av.x*wl.x; accL[0].y += av.x*wl.y; accL[0].z += av.x*wl.z; accL[0].w += av.x*wl.w;
            accL[1].x += av.y*wl.x; accL[1].y += av.y*wl.y; accL[1].z += av.y*wl.z; accL[1].w += av.y*wl.w;
            accL[2].x += av.z*wl.x; accL[2].y += av.z*wl.y; accL[2].z += av.z*wl.z; accL[2].w += av.z*wl.w;
            accL[3].x += av.w*wl.x; accL[3].y += av.w*wl.y; accL[3].z += av.w*wl.z; accL[3].w += av.w*wl.w;
            accR[0].x += av.x*wr.x; accR[0].y += av.x*wr.y; accR[0].z += av.x*wr.z; accR[0].w += av.x*wr.w;
            accR[1].x += av.y*wr.x; accR[1].y += av.y*wr.y; accR[1].z += av.y*wr.z; accR[1].w += av.y*wr.w;
            accR[2].x += av.z*wr.x; accR[2].y += av.z*wr.y; accR[2].z += av.z*wr.z; accR[2].w += av.z*wr.w;
            accR[3].x += av.w*wr.x; accR[3].y += av.w*wr.y; accR[3].z += av.w*wr.z; accR[3].w += av.w*wr.w;
        }
    }
    const float4 bvL = *(const float4*)(bL + tj);
    const float4 bvR = *(const float4*)(bR + tj);
    #pragma unroll
    for (int u = 0; u < 4; ++u) {
        int n = n0 + tn + u;
        if (n < nn) {
            float4 o;
            o.x = accL[u].x + bvL.x; o.y = accL[u].y + bvL.y;
            o.z = accL[u].z + bvL.z; o.w = accL[u].w + bvL.w;
            *(float4*)(outL + (size_t)n*HC + tj) = o;
            o.x = accR[u].x + bvR.x; o.y = accR[u].y + bvR.y;
            o.z = accR[u].z + bvR.z; o.w = accR[u].w + bvR.w;
            *(float4*)(outR + (size_t)n*HC + tj) = o;
        }
    }
}

// cross-lane helpers.
// BCH: compile-time ds_swizzle broadcast of a half2 word (DS pipe):
//   imm = (j<<5)|0x10 -> lane i reads lane (i&0x10)|j, i.e. each 16-lane row
//   gets pair j held by its own lane j. j in 0..7 covers the 16 f16 values.
#define BCH(bits, j) __builtin_bit_cast(h2, \
    __builtin_amdgcn_ds_swizzle((bits), ((j) << 5) | 0x10))

// DPP rotate within each 16-lane row: pure VALU cross-lane, short latency.
// ctrl: 0x121 = row_ror:1, 0x122 = row_ror:2, 0x124 = row_ror:4, 0x128 = row_ror:8
template<int CTRL>
__device__ __forceinline__ float dpp_ror(float v) {
    return __int_as_float(__builtin_amdgcn_update_dpp(
        0, __float_as_int(v), CTRL, 0xF, 0xF, true));
}

// per-edge logit+exp+accumulate — f16-pair hybrid:
//   em via 8 ds_swizzle half2 broadcasts (DS pipe, was 16 f32 broadcasts)
//   consumed by 8 v_dot2_f32_f16 (f32 accumulate); head reduction on the
//   VALU via 4 short-latency DPP rotate-adds.
__device__ __forceinline__ void edge_step9(
    int eab, float xlv, float xrc, float attc,
    h2 wp0, h2 wp1, h2 wp2, h2 wp3, h2 wp4, h2 wp5, h2 wp6, h2 wp7,
    float gate, float& acc, float& l) {
    float m0 = FDOT2(wp1, BCH(eab, 1), FDOT2(wp0, BCH(eab, 0), 0.f));
    float m1 = FDOT2(wp3, BCH(eab, 3), FDOT2(wp2, BCH(eab, 2), 0.f));
    float m2 = FDOT2(wp5, BCH(eab, 5), FDOT2(wp4, BCH(eab, 4), 0.f));
    float m3 = FDOT2(wp7, BCH(eab, 7), FDOT2(wp6, BCH(eab, 6), 0.f));
    float v = (xlv + xrc) + ((m0 + m1) + (m2 + m3));
    v = fmaxf(v, 0.f) + NEG_SLOPE * fminf(v, 0.f);
    v *= attc;
    // full 16-lane-row sum, broadcast to all lanes (rotation group => exact)
    v += dpp_ror<0x121>(v);
    v += dpp_ror<0x122>(v);
    v += dpp_ror<0x124>(v);
    v += dpp_ror<0x128>(v);
    const float pt = __expf(v) * gate;
    acc += pt * xlv;
    l   += pt;
}

// ====== fused attention v9: 1 node per 80-thread group, 2 edges/iter ========
// thread = channel c (head = c>>4). Lane-sliced f16-pair eattr (1 dword =
// half2 per thread per edge, prefetched one iteration ahead); em via 8
// half2 ds_swizzle broadcasts + v_dot2_f32_f16; head-reduce via DPP.
// 2-edge unroll with 4-deep prefetch pipeline: all loads issued at iteration
// top, no intra-iteration dependent chains. src_s is pre-scaled by HC. Pads
// make all prefetches in-bounds; pad rows are zeroed (exp(0-logit) finite,
// killed by gate=0).
template<bool SORTED>
__global__ __launch_bounds__(320) void k_fused9(
    const float* __restrict__ xl, const float* __restrict__ xr,
    const void* __restrict__ eav,  // int half2-rows if SORTED, f32 rows else
    const float* __restrict__ we, const float* __restrict__ att,
    const int* __restrict__ perm, const int* __restrict__ src_s,
    const int* __restrict__ rowstart, const int* __restrict__ nodeord,
    const float* __restrict__ bias, float* __restrict__ out, int relu) {
    const int t = threadIdx.x;
    const int group = t / 80;
    const int c = t - group * 80;
    const int idx = blockIdx.x * 4 + group;
    if (idx >= N_NODES) return;
    const int n = nodeord[idx];

    const int* eh = (const int*)eav;     // SORTED path
    const float* ef = (const float*)eav; // fallback path
    const int pj = c & 7;                // which half2 pair this lane holds

    // weights as 8 half2 pairs (f16 rounding; values ~N(0,1/16) -> err ~5e-4)
    const float4* w4 = (const float4*)(we + c * ED_DIM);
    const float4 wa = w4[0], wb = w4[1], wc = w4[2], wd = w4[3];
    const h2 wp0 = PKH2(wa.x, wa.y), wp1 = PKH2(wa.z, wa.w);
    const h2 wp2 = PKH2(wb.x, wb.y), wp3 = PKH2(wb.z, wb.w);
    const h2 wp4 = PKH2(wc.x, wc.y), wp5 = PKH2(wc.z, wc.w);
    const h2 wp6 = PKH2(wd.x, wd.y), wp7 = PKH2(wd.z, wd.w);

    const float attc = att[c];
    const float bc   = bias[c];
    const float xrc  = xr[n * HC + c];

    const int rs = rowstart[n], re = rowstart[n + 1];
    float l = 0.f, acc = 0.f;

    if (rs < re) {
        // preamble: values for p, p+1 in flight; src offsets for p+2, p+3
        const int o0 = src_s[rs];
        const int o1 = src_s[rs + 1];
        int sA = src_s[rs + 2];
        int sB = src_s[rs + 3];
        float xlA = xl[o0 + c];
        float xlB = xl[o1 + c];
        int eaA, eaB;
        if (SORTED) {
            eaA = eh[(size_t)rs * 8 + pj];
            eaB = eh[(size_t)(rs + 1) * 8 + pj];
        } else {
            const int e0 = perm[rs], e1 = perm[rs + 1];
            const float2 f0 = *(const float2*)(ef + (size_t)e0 * ED_DIM + 2 * pj);
            const float2 f1 = *(const float2*)(ef + (size_t)e1 * ED_DIM + 2 * pj);
            eaA = __builtin_bit_cast(int, PKH2(f0.x, f0.y));
            eaB = __builtin_bit_cast(int, PKH2(f1.x, f1.y));
        }

        for (int p = rs; p < re; p += 2) {
            const float xl0 = xlA, xl1 = xlB;
            const int ea0 = eaA, ea1 = eaB;
            // issue next loads (for p+2, p+3); no dependent chains in-iter
            xlA = xl[sA + c];
            xlB = xl[sB + c];
            sA = src_s[p + 4];
            sB = src_s[p + 5];
            if (SORTED) {
                eaA = eh[(size_t)(p + 2) * 8 + pj];
                eaB = eh[(size_t)(p + 3) * 8 + pj];
            } else {
                const int en0 = perm[p + 2], en1 = perm[p + 3];
                const float2 f0 = *(const float2*)(ef + (size_t)en0 * ED_DIM + 2 * pj);
                const float2 f1 = *(const float2*)(ef + (size_t)en1 * ED_DIM + 2 * pj);
                eaA = __builtin_bit_cast(int, PKH2(f0.x, f0.y));
                eaB = __builtin_bit_cast(int, PKH2(f1.x, f1.y));
            }

            edge_step9(ea0, xl0, xrc, attc, wp0, wp1, wp2, wp3, wp4, wp5, wp6, wp7,
                       1.f, acc, l);
            const float g1 = (p + 1 < re) ? 1.f : 0.f;
            edge_step9(ea1, xl1, xrc, attc, wp0, wp1, wp2, wp3, wp4, wp5, wp6, wp7,
                       g1, acc, l);
        }
    }
    float o = acc / (l + 1e-16f) + bc;
    if (relu) o = fmaxf(o, 0.f);
    out[n * HC + c] = o;
}

extern "C" void kernel_launch(void* const* d_in, const int* in_sizes, int n_in,
                              void* d_out, int out_size, void* d_ws, size_t ws_size,
                              hipStream_t stream) {
    (void)in_sizes; (void)n_in; (void)out_size;
    const float* x     = (const float*)d_in[0];
    const int*   ei    = (const int*)d_in[1];
    const float* eattr = (const float*)d_in[2];
    const int* srcp = ei;
    const int* dstp = ei + N_EDGES;

    // workspace layout
    float* h      = (float*)d_ws;                            // N*80
    float* xl     = h  + (size_t)N_NODES*HC;                 // N*80
    float* xr     = xl + (size_t)N_NODES*HC;                 // N*80
    int* rowstart = (int*)(xr + (size_t)N_NODES*HC);         // N+1
    int* cursor   = rowstart + (N_NODES + 1);                // N
    int* perm     = cursor + N_NODES;                        // E + EPAD
    int* src_s    = perm + N_EDGES + EPAD;                   // E + EPAD
    int* partial  = src_s + N_EDGES + EPAD;                  // SCAN_G
    int* blockoff = partial + SCAN_G;                        // SCAN_G
    int* dhist    = blockoff + SCAN_G;                       // DBIN
    int* dcur     = dhist + DBIN;                            // DBIN
    int* nodeord  = dcur + DBIN;                             // N
    // 64B-align eattr_h: rows are 32B (8 half2 words), written with int4 pairs
    int* eattr_h = (int*)(((uintptr_t)(nodeord + N_NODES) + 63) &
                          ~(uintptr_t)63);                   // (E+8)*8 ints
    float* outp   = (float*)d_out;

    const size_t need_sorted =
        (size_t)((char*)(eattr_h + (size_t)(N_EDGES + EPAD) * 8) - (char*)d_ws);
    const bool use_sorted = (ws_size >= need_sorted);

    const dim3 bx(320);
    const dim3 gx((N_NODES + 63) / 64);
    const dim3 gf((N_NODES + 3) / 4);
    const dim3 geb((N_EDGES + 255) / 256);
    const dim3 gnb((N_NODES + 255) / 256);

    // ---- build CSR by destination + degree-sorted node order (once) ----
    hipMemsetAsync(cursor, 0, (size_t)N_NODES * sizeof(int), stream);
    hipMemsetAsync(dhist, 0, DBIN * sizeof(int), stream);
    k_hist<<<geb, 256, 0, stream>>>(dstp, cursor);
    k_part<<<SCAN_G, SCAN_B, 0, stream>>>(cursor, partial);
    k_scanp<<<1, 512, 0, stream>>>(partial, blockoff, rowstart);
    k_apply<<<SCAN_G, SCAN_B, 0, stream>>>(cursor, blockoff, rowstart);
    k_deghist<<<gnb, 256, 0, stream>>>(cursor, dhist);
    k_degoff<<<1, 64, 0, stream>>>(dhist, dcur, perm, src_s);
    k_degplace<<<gnb, 256, 0, stream>>>(cursor, dcur, nodeord);
    hipMemsetAsync(cursor, 0, (size_t)N_NODES * sizeof(int), stream);
    if (use_sorted) {
        k_place<true><<<geb, 256, 0, stream>>>(srcp, dstp, rowstart, cursor,
                                               perm, src_s, eattr, eattr_h);
    } else {
        k_place<false><<<geb, 256, 0, stream>>>(srcp, dstp, rowstart, cursor,
                                                perm, src_s, eattr, eattr_h);
    }

    for (int L = 0; L < 3; ++L) {
        const float* in   = (L == 0) ? x : h;
        float*       oacc = (L == 2) ? outp : h;
        const float* wl   = (const float*)d_in[3 + L*7 + 0];
        const float* bl   = (const float*)d_in[3 + L*7 + 1];
        const float* wr   = (const float*)d_in[3 + L*7 + 2];
        const float* br   = (const float*)d_in[3 + L*7 + 3];
        const float* we   = (const float*)d_in[3 + L*7 + 4];
        const float* att  = (const float*)d_in[3 + L*7 + 5];
        const float* bias = (const float*)d_in[3 + L*7 + 6];

        if (L == 0) {
            k_xform2<F_IN><<<gx, bx, 0, stream>>>(in, wl, bl, wr, br, xl, xr, N_NODES);
        } else {
            k_xform2<HC><<<gx, bx, 0, stream>>>(in, wl, bl, wr, br, xl, xr, N_NODES);
        }
        if (use_sorted) {
            k_fused9<true><<<gf, bx, 0, stream>>>(xl, xr, eattr_h, we, att, perm,
                                                  src_s, rowstart, nodeord, bias,
                                                  oacc, (L < 2) ? 1 : 0);
        } else {
            k_fused9<false><<<gf, bx, 0, stream>>>(xl, xr, eattr, we, att, perm,
                                                   src_s, rowstart, nodeord, bias,
                                                   oacc, (L < 2) ? 1 : 0);
        }
    }
}